// Round 8
// baseline (435.879 us; speedup 1.0000x reference)
//
#include <hip/hip_runtime.h>
#include <stdint.h>

// EdgeNetwork per-edge MLP — round 8: occupancy 2x.
//  vs r7: single change — __launch_bounds__(256, 4): 4 blocks/CU (16 waves/CU).
//  VGPR 112 <= 128 cap, LDS 39936*4 = 159744 <= 163840 (fits exactly).
//  r7 was ~40% memory-latency idle at 1.7 waves/SIMD; this doubles resident
//  waves so gather latency hides behind wave-level parallelism.

#define TPB 256
#define NEG_SLOPE 0.1f
#define LN_EPS    1e-5f

typedef __attribute__((ext_vector_type(8))) short short8;   // 8 bf16 (4 VGPR)
typedef __attribute__((ext_vector_type(4))) float f32x4;    // 4 f32

__device__ __forceinline__ uint32_t fb(float x) {
  union { float f; uint32_t u; } c; c.f = x; return c.u;
}
__device__ __forceinline__ float bf(uint32_t x) {
  union { uint32_t u; float f; } c; c.u = x; return c.f;
}
// pack 2 f32 -> 2 bf16 (round-half-up) in one v_perm after two adds
__device__ __forceinline__ uint32_t pkbf(float a, float b) {
  return __builtin_amdgcn_perm(fb(b) + 0x8000u, fb(a) + 0x8000u, 0x07060302u);
}
__device__ __forceinline__ short8 cvt8(f32x4 a, f32x4 b) {
  union { short8 s; uint32_t u[4]; } r;
  r.u[0] = pkbf(a[0], a[1]);
  r.u[1] = pkbf(a[2], a[3]);
  r.u[2] = pkbf(b[0], b[1]);
  r.u[3] = pkbf(b[2], b[3]);
  return r.s;
}
__device__ __forceinline__ short bf16rne(float x) {   // staging (one-time)
  uint32_t u = fb(x);
  return (short)((u + 0x7fffu + ((u >> 16) & 1u)) >> 16);
}

// DPP rotation-allreduce across each row of 16 lanes (pure VALU).
template <int CTRL>
__device__ __forceinline__ float dppadd(float v) {
  int r = __builtin_amdgcn_update_dpp(0, (int)fb(v), CTRL, 0xf, 0xf, true);
  return v + bf((uint32_t)r);
}
__device__ __forceinline__ float rowsum16(float v) {
  v = dppadd<0x121>(v);   // row_ror:1
  v = dppadd<0x122>(v);   // row_ror:2
  v = dppadd<0x124>(v);   // row_ror:4
  v = dppadd<0x128>(v);   // row_ror:8
  return v;
}
__device__ __forceinline__ void redsum16(f32x4& v) {
  #pragma unroll
  for (int c = 0; c < 4; ++c) v[c] = rowsum16(v[c]);
}

__global__ __launch_bounds__(TPB, 4)
void edge_mlp_mfma(const float* __restrict__ nf, const int* __restrict__ ei,
                   const float* __restrict__ ea,
                   const float* __restrict__ W1, const float* __restrict__ b1,
                   const float* __restrict__ g1, const float* __restrict__ be1,
                   const float* __restrict__ W2, const float* __restrict__ b2,
                   const float* __restrict__ g2, const float* __restrict__ be2,
                   const float* __restrict__ W3, const float* __restrict__ b3,
                   float* __restrict__ out, int E, int ntiles) {
  __shared__ short W1T[64 * 168];      // [n][k], k 0..159 (144 real + 16 zero)
  __shared__ short W2T[64 * 72];       // [n][k], stride 72
  __shared__ short HB[4][16 * 72];     // per-wave h1 tile (16 edges x 64 + pad)

  const int tid  = threadIdx.x;
  const int lane = tid & 63;
  const int wv   = tid >> 6;
  const int ln   = lane & 15;
  const int quad = lane >> 4;

  // ---- Stage W1^T, W2^T as bf16 into LDS ----
  for (int i = tid; i < 9216; i += TPB) {
    int n = i & 63, k = i >> 6;
    W1T[n * 168 + k] = bf16rne(W1[k * 64 + n]);
  }
  for (int i = tid; i < 1024; i += TPB) {            // zero-pad k in [144,160)
    int n = i & 63, k = 144 + (i >> 6);
    W1T[n * 168 + k] = 0;
  }
  for (int i = tid; i < 4096; i += TPB) {
    int n = i & 63, k = i >> 6;
    W2T[n * 72 + k] = bf16rne(W2[k * 64 + n]);
  }
  __syncthreads();   // the ONLY block barrier

  // ---- Per-lane n-indexed params (n = ln + 16*jt) ----
  float b1v[4], g1v[4], be1v[4], b2v[4], g2v[4], be2v[4], W3v[4];
  #pragma unroll
  for (int jt = 0; jt < 4; ++jt) {
    int n = ln + 16 * jt;
    b1v[jt] = b1[n];  g1v[jt] = g1[n];  be1v[jt] = be1[n];
    b2v[jt] = b2[n];  g2v[jt] = g2[n];  be2v[jt] = be2[n];
    W3v[jt] = W3[n];
  }
  const float b3s = b3[0];

  // int64-vs-int32 index sniff (validated rounds 3-7)
  const bool idx64 = (__ballot(ei[2 * lane + 1] == 0) == ~0ull);

  // ---- Prefetched indices for the first tile ----
  int sI[4], dI[4], eC[4];
  {
    const int ebase = blockIdx.x * 256 + wv * 64;
    #pragma unroll
    for (int mt = 0; mt < 4; ++mt) {
      int el = ebase + mt * 16 + ln;
      int ec = el < E ? el : E - 1;
      eC[mt] = ec;
      if (idx64) { sI[mt] = ei[2 * ec]; dI[mt] = ei[2 * (E + ec)]; }
      else       { sI[mt] = ei[ec];     dI[mt] = ei[E + ec]; }
    }
  }

  for (int tile = blockIdx.x; tile < ntiles; tile += gridDim.x) {
    const int ebase = tile * 256 + wv * 64;

    // ---- Batch gather: all 40 loads issued together, cvt by arrival ----
    short8 afr[4][5];
    #pragma unroll
    for (int mt = 0; mt < 4; ++mt) {
      const float* sp = nf + (size_t)sI[mt] * 64 + quad * 8;
      const float* dp = nf + (size_t)dI[mt] * 64 + quad * 8;
      const float* ap = ea + (size_t)eC[mt] * 16 + (quad & 1) * 8;
      f32x4 c0 = *(const f32x4*)sp;        f32x4 c1 = *(const f32x4*)(sp + 4);
      f32x4 c2 = *(const f32x4*)(sp + 32); f32x4 c3 = *(const f32x4*)(sp + 36);
      f32x4 c4 = *(const f32x4*)dp;        f32x4 c5 = *(const f32x4*)(dp + 4);
      f32x4 c6 = *(const f32x4*)(dp + 32); f32x4 c7 = *(const f32x4*)(dp + 36);
      f32x4 c8 = *(const f32x4*)ap;        f32x4 c9 = *(const f32x4*)(ap + 4);
      afr[mt][0] = cvt8(c0, c1);
      afr[mt][1] = cvt8(c2, c3);
      afr[mt][2] = cvt8(c4, c5);
      afr[mt][3] = cvt8(c6, c7);
      afr[mt][4] = cvt8(c8, c9);   // k>=144 lanes: B rows are zero, value moot
    }

    // ---- Layer 1: 80 MFMAs (bias pre-folded into acc init) ----
    f32x4 acc[4][4];                       // [mt][jt]
    #pragma unroll
    for (int mt = 0; mt < 4; ++mt)
      #pragma unroll
      for (int jt = 0; jt < 4; ++jt) acc[mt][jt] = (f32x4)(b1v[jt]);

    #pragma unroll
    for (int t = 0; t < 5; ++t)
      #pragma unroll
      for (int jt = 0; jt < 4; ++jt) {
        short8 bfr = *(const short8*)&W1T[(jt * 16 + ln) * 168 + t * 32 + quad * 8];
        #pragma unroll
        for (int mt = 0; mt < 4; ++mt)
          acc[mt][jt] = __builtin_amdgcn_mfma_f32_16x16x32_bf16(
              afr[mt][t], bfr, acc[mt][jt], 0, 0, 0);
      }

    // ---- Prefetch next tile's indices (latency hides behind epilogue) ----
    {
      int ntile = tile + gridDim.x;
      if (ntile < ntiles) {
        const int nb = ntile * 256 + wv * 64;
        #pragma unroll
        for (int mt = 0; mt < 4; ++mt) {
          int el = nb + mt * 16 + ln;
          int ec = el < E ? el : E - 1;
          eC[mt] = ec;
          if (idx64) { sI[mt] = ei[2 * ec]; dI[mt] = ei[2 * (E + ec)]; }
          else       { sI[mt] = ei[ec];     dI[mt] = ei[E + ec]; }
        }
      }
    }

    // ---- Epilogue per mt (wave-private; DPP reductions, no block barriers) --
    #pragma unroll
    for (int mt = 0; mt < 4; ++mt) {
      f32x4 sv = acc[mt][0] + acc[mt][1] + acc[mt][2] + acc[mt][3];
      f32x4 qv = acc[mt][0] * acc[mt][0] + acc[mt][1] * acc[mt][1]
               + acc[mt][2] * acc[mt][2] + acc[mt][3] * acc[mt][3];
      redsum16(sv);
      redsum16(qv);
      f32x4 mu  = sv * (1.f / 64.f);
      f32x4 var = qv * (1.f / 64.f) - mu * mu;
      f32x4 rs;
      rs[0] = rsqrtf(var[0] + LN_EPS); rs[1] = rsqrtf(var[1] + LN_EPS);
      rs[2] = rsqrtf(var[2] + LN_EPS); rs[3] = rsqrtf(var[3] + LN_EPS);

      #pragma unroll
      for (int jt = 0; jt < 4; ++jt)
        #pragma unroll
        for (int r = 0; r < 4; ++r) {
          float h = (acc[mt][jt][r] - mu[r]) * rs[r] * g1v[jt] + be1v[jt];
          h = fmaxf(h, NEG_SLOPE * h);
          HB[wv][(quad * 4 + r) * 72 + ln + 16 * jt] =
              (short)((fb(h) + 0x8000u) >> 16);
        }
      // wave-private handoff: DS is in-order per wave; drain writes then read
      asm volatile("s_waitcnt lgkmcnt(0)" ::: "memory");

      f32x4 acc2[4];
      #pragma unroll
      for (int jt = 0; jt < 4; ++jt) acc2[jt] = (f32x4)(b2v[jt]);
      #pragma unroll
      for (int t2 = 0; t2 < 2; ++t2) {
        short8 a2 = *(const short8*)&HB[wv][ln * 72 + t2 * 32 + quad * 8];
        #pragma unroll
        for (int jt = 0; jt < 4; ++jt) {
          short8 w2f = *(const short8*)&W2T[(jt * 16 + ln) * 72 + t2 * 32 + quad * 8];
          acc2[jt] = __builtin_amdgcn_mfma_f32_16x16x32_bf16(
              a2, w2f, acc2[jt], 0, 0, 0);
        }
      }

      f32x4 s2 = acc2[0] + acc2[1] + acc2[2] + acc2[3];
      f32x4 q2 = acc2[0] * acc2[0] + acc2[1] * acc2[1]
               + acc2[2] * acc2[2] + acc2[3] * acc2[3];
      redsum16(s2);
      redsum16(q2);
      f32x4 mu2  = s2 * (1.f / 64.f);
      f32x4 var2 = q2 * (1.f / 64.f) - mu2 * mu2;
      f32x4 rs2;
      rs2[0] = rsqrtf(var2[0] + LN_EPS); rs2[1] = rsqrtf(var2[1] + LN_EPS);
      rs2[2] = rsqrtf(var2[2] + LN_EPS); rs2[3] = rsqrtf(var2[3] + LN_EPS);

      f32x4 po = (f32x4)0.f;
      #pragma unroll
      for (int jt = 0; jt < 4; ++jt)
        #pragma unroll
        for (int r = 0; r < 4; ++r) {
          float h = (acc2[jt][r] - mu2[r]) * rs2[r] * g2v[jt] + be2v[jt];
          h = fmaxf(h, NEG_SLOPE * h);
          po[r] = fmaf(h, W3v[jt], po[r]);
        }
      redsum16(po);

      if (ln < 4) {       // lanes 0-3 of each quad store edges quad*4 + ln
        int e = ebase + mt * 16 + quad * 4 + ln;
        if (e < E) {
          float v = (ln == 0) ? po[0] : (ln == 1) ? po[1] : (ln == 2) ? po[2] : po[3];
          out[e] = v + b3s;
        }
      }
    }
  }
}

extern "C" void kernel_launch(void* const* d_in, const int* in_sizes, int n_in,
                              void* d_out, int out_size, void* d_ws, size_t ws_size,
                              hipStream_t stream) {
  const float* nf = (const float*)d_in[0];
  const int*   ei = (const int*)d_in[1];
  const float* ea = (const float*)d_in[2];

  const int E = out_size;
  const int ntiles = (E + 255) / 256;
  const int blocks = ntiles < 1024 ? ntiles : 1024;

  edge_mlp_mfma<<<blocks, TPB, 0, stream>>>(
      nf, ei, ea,
      (const float*)d_in[3],  (const float*)d_in[4],
      (const float*)d_in[5],  (const float*)d_in[6],
      (const float*)d_in[7],  (const float*)d_in[8],
      (const float*)d_in[9],  (const float*)d_in[10],
      (const float*)d_in[11], (const float*)d_in[12],
      (float*)d_out, E, ntiles);
}